// Round 8
// baseline (2371.328 us; speedup 1.0000x reference)
//
#include <hip/hip_runtime.h>

// RNNSequenceEncoder: B=256, T=256, IN=128, H=1024
// Round-8: epoch-tagged state packets — the stage IS the sync.
// Rounds 4/7 paid 3-4 serialized coherence-point legs per step (store-ack,
// flag store, flag propagate, poll, stage load). Now state is exchanged as
// f32 words whose 2 LSBs carry an epoch tag (1+((v-1)%3); 0 = empty). The
// consumer loads the row-block tile (sc0 sc1), validates every word's tag,
// and retries until fresh: data+validity in ONE round trip, no flags, no
// producer ack-wait. Word-level (4B) CP write atomicity is the only HW
// assumption (each word independently tagged -> torn 16B loads harmless).
// Back-pressure: validating the full region at stage t proves all peers
// passed their stage t-1, so the 2-buffer scheme cannot be overrun.
// Tag aliasing across calls (0xAA poison has tag 2) is killed by zero-fill
// init (tag 0 never valid) + the tag-cycle (period 3 vs buffer period 2).
// Own 128-col slice goes register->LDS directly (skips CP + self-retry).
//   - 128 WGs x 512 threads: row-block r (16 batch rows) x 8 WGs (128 cols)
//   - W_rec slice in VGPRs (operand-swap: lane's 4 outputs = 4 consecutive
//     cols -> one 16B tagged store); state tile in LDS (XOR swizzle)
//   - epilogue: one-shot sc0sc1 grid barrier (proven), W_out, 256MB broadcast

#define Bdim 256
#define Tdim 256
#define INdim 128
#define Hdim 1024

typedef __attribute__((ext_vector_type(8))) __bf16 bf16x8;
typedef __attribute__((ext_vector_type(4))) float f32x4;
typedef __attribute__((ext_vector_type(4))) int i32x4;
typedef __attribute__((ext_vector_type(2))) int i32x2;

#define OUT_BYTES ((size_t)Bdim * Tdim * Hdim * 4)   /* 256 MB */
#define SBYTES_F32 ((size_t)Bdim * Hdim * 4)         /* one f32 state buffer: 1 MB */
#define CNT_BYTES 32768
#define SCRATCH_BYTES (CNT_BYTES + 2 * SBYTES_F32)   /* 2.03 MB, = 520*4096 */

// --- device-coherent ops (bypass L1+L2; visible device-wide; PROVEN) ---
static __device__ __forceinline__ void st_b128_c(void* p, i32x4 v) {
  asm volatile("global_store_dwordx4 %0, %1, off sc0 sc1" :: "v"(p), "v"(v) : "memory");
}
static __device__ __forceinline__ void st_b32_c(void* p, unsigned v) {
  asm volatile("global_store_dword %0, %1, off sc0 sc1" :: "v"(p), "v"(v) : "memory");
}
static __device__ __forceinline__ unsigned ld_b32_c(const void* p) {
  unsigned v;
  asm volatile("global_load_dword %0, %1, off sc0 sc1\n\ts_waitcnt vmcnt(0)"
               : "=v"(v) : "v"(p) : "memory");
  return v;
}
static __device__ __forceinline__ i32x4 ld_b128_c(const void* p) {
  i32x4 v;
  asm volatile("global_load_dwordx4 %0, %1, off sc0 sc1" : "=v"(v) : "v"(p) : "memory");
  return v;
}
static __device__ __forceinline__ void wait_vm0() {
  asm volatile("s_waitcnt vmcnt(0)" ::: "memory");
}

static __device__ __forceinline__ bf16x8 cvt8(f32x4 lo, f32x4 hi) {
  bf16x8 r;
  r[0] = (__bf16)lo[0]; r[1] = (__bf16)lo[1]; r[2] = (__bf16)lo[2]; r[3] = (__bf16)lo[3];
  r[4] = (__bf16)hi[0]; r[5] = (__bf16)hi[1]; r[6] = (__bf16)hi[2]; r[7] = (__bf16)hi[3];
  return r;
}
// two tagged f32 words -> one dword of 2 bf16 (tags masked before RNE cvt)
static __device__ __forceinline__ unsigned cvt2(int a, int b) {
  float fa = __builtin_bit_cast(float, (unsigned)a & ~3u);
  float fb = __builtin_bit_cast(float, (unsigned)b & ~3u);
  unsigned sa = (unsigned)__builtin_bit_cast(unsigned short, (__bf16)fa);
  unsigned sb = (unsigned)__builtin_bit_cast(unsigned short, (__bf16)fb);
  return (sb << 16) | sa;
}
static __device__ __forceinline__ unsigned tagw(float f, unsigned tag) {
  return (__builtin_bit_cast(unsigned, f) & ~3u) | tag;
}

// Stage the row-block's 16x1024 TAGGED f32 state -> bf16 LDS tile (XOR
// swizzle on 16B bf16 chunks: chunk ch lands at ch ^ (row&7)). Retries the
// CP loads until every word carries `tag`. Threads whose col-chunk belongs
// to this WG's own slice (ch>>4 == cown) skip: self-written from registers.
static __device__ __forceinline__ void stage_tagged(const unsigned* __restrict__ src,
                                                    __bf16* sA, int tid, int cown,
                                                    unsigned tag) {
  int ch = tid & 127;               // 8-col chunk index, same for all 4 rows
  if ((ch >> 4) == cown) return;
  int row0 = tid >> 7;              // rows row0, +4, +8, +12
  const unsigned* a0 = src + (size_t)(row0 + 0) * Hdim + ch * 8;
  const unsigned* a1 = src + (size_t)(row0 + 4) * Hdim + ch * 8;
  const unsigned* a2 = src + (size_t)(row0 + 8) * Hdim + ch * 8;
  const unsigned* a3 = src + (size_t)(row0 + 12) * Hdim + ch * 8;
  i32x4 d0, d1, d2, d3, d4, d5, d6, d7;
  for (;;) {
    d0 = ld_b128_c(a0); d1 = ld_b128_c(a0 + 4);
    d2 = ld_b128_c(a1); d3 = ld_b128_c(a1 + 4);
    d4 = ld_b128_c(a2); d5 = ld_b128_c(a2 + 4);
    d6 = ld_b128_c(a3); d7 = ld_b128_c(a3 + 4);
    wait_vm0();
    unsigned bad = 0;
#define CHK(dd) bad |= (unsigned)((dd[0] ^ (int)tag) | (dd[1] ^ (int)tag) | \
                                  (dd[2] ^ (int)tag) | (dd[3] ^ (int)tag))
    CHK(d0); CHK(d1); CHK(d2); CHK(d3); CHK(d4); CHK(d5); CHK(d6); CHK(d7);
#undef CHK
    if ((bad & 3u) == 0u) break;
    __builtin_amdgcn_s_sleep(4);  // backoff: avoid CP read-flood congestion
  }
#define PUT(rw, lo, hi)                                                        \
  {                                                                            \
    int rr = (rw);                                                             \
    i32x4 o = {(int)cvt2(lo[0], lo[1]), (int)cvt2(lo[2], lo[3]),               \
               (int)cvt2(hi[0], hi[1]), (int)cvt2(hi[2], hi[3])};              \
    *(i32x4*)(sA + (size_t)rr * Hdim + ((ch ^ (rr & 7)) << 3)) = o;            \
  }
  PUT(row0 + 0, d0, d1); PUT(row0 + 4, d2, d3);
  PUT(row0 + 8, d4, d5); PUT(row0 + 12, d6, d7);
#undef PUT
}

// state fragment from LDS: lane holds rows[lane&15][k0..k0+7], k0=kk*32+(lane>>4)*8,
// through the XOR swizzle. A/B use identical K-packing so HW K-permutation cancels.
static __device__ __forceinline__ bf16x8 afrag(const __bf16* sA, int lane, int kk) {
  int row = lane & 15;
  int chq = kk * 4 + (lane >> 4);
  return *(const bf16x8*)(sA + (size_t)row * Hdim + ((chq ^ (row & 7)) << 3));
}

__global__ void zero_ws(i32x4* p) {
  p[(size_t)blockIdx.x * 256 + threadIdx.x] = (i32x4){0, 0, 0, 0};
}

__global__ void __launch_bounds__(512, 1)
rnn_fused(const float* __restrict__ x, const float* __restrict__ W_in,
          const float* __restrict__ b_in, const float* __restrict__ W_rec,
          const float* __restrict__ b_rec, const float* __restrict__ W_out,
          const float* __restrict__ b_out, float* __restrict__ out,
          char* __restrict__ scratch) {
  __shared__ __align__(16) __bf16 sA[16 * Hdim];  // 32 KB

  unsigned* counters = (unsigned*)scratch;
  unsigned* buf0 = (unsigned*)(scratch + CNT_BYTES);           // tagged f32 state
  unsigned* buf1 = buf0 + (size_t)Bdim * Hdim;

  int wg = blockIdx.x;               // 0..127
  int idx = wg >> 3;
  int r = (wg & 7) + 8 * (idx & 1);  // row block 0..15
  int c = idx >> 1;                  // col chunk 0..7 (128 H cols)
  int tid = threadIdx.x;
  int lane = tid & 63;
  int ww = tid >> 6;                 // wave 0..7
  int kgrp = lane >> 4;

  int colw = c * 128 + ww * 16 + (lane & 15);  // weight row this lane carries
  int colb = c * 128 + ww * 16 + kgrp * 4;     // first of 4 output cols
  int grow = 16 * r + (lane & 15);             // batch row this lane owns

  unsigned* gflags = counters + 4096;          // epilogue one-shot flags

  // self-write target in LDS (own slice, bypasses CP): 8B at swizzled chunk
  int selfrow = lane & 15;
  int selfch = 16 * c + 2 * ww + (kgrp >> 1);
  __bf16* selfdst = sA + (size_t)selfrow * Hdim +
                    ((selfch ^ (selfrow & 7)) << 3) + (kgrp & 1) * 4;

  // --- preload weights (normal cached loads) ---
  bf16x8 wrec[32];  // W_rec rows as A-operand fragments (128 VGPRs)
#pragma unroll
  for (int kk = 0; kk < 32; ++kk) {
    const float* p = W_rec + (size_t)colw * Hdim + kk * 32 + kgrp * 8;
    wrec[kk] = cvt8(*(const f32x4*)p, *(const f32x4*)(p + 4));
  }
  bf16x8 win[4];
#pragma unroll
  for (int kk = 0; kk < 4; ++kk) {
    const float* p = W_in + (size_t)colw * INdim + kk * 32 + kgrp * 8;
    win[kk] = cvt8(*(const f32x4*)p, *(const f32x4*)(p + 4));
  }
  f32x4 brec4 = *(const f32x4*)(b_rec + colb);
  f32x4 bin4 = *(const f32x4*)(b_in + colb);
  int xk0 = kgrp * 8;

  // --- phase 0: v1 = ext_0 -> tagged store (tag 1) + self LDS write ---
  {
    f32x4 e = {0.f, 0.f, 0.f, 0.f};
#pragma unroll
    for (int kk = 0; kk < 4; ++kk) {
      const float* p = x + ((size_t)grow * Tdim + 0) * INdim + kk * 32 + xk0;
      e = __builtin_amdgcn_mfma_f32_16x16x32_bf16(
          win[kk], cvt8(*(const f32x4*)p, *(const f32x4*)(p + 4)), e, 0, 0, 0);
    }
    i32x4 w = {(int)tagw(e[0] + bin4[0], 1u), (int)tagw(e[1] + bin4[1], 1u),
               (int)tagw(e[2] + bin4[2], 1u), (int)tagw(e[3] + bin4[3], 1u)};
    st_b128_c(buf0 + (size_t)grow * Hdim + colb, w);
    *(i32x2*)selfdst = (i32x2){(int)cvt2(w[0], w[1]), (int)cvt2(w[2], w[3])};
  }

  // prologue: x_1 into registers (consumed by iter 0's ext MFMA)
  f32x4 xlo[4], xhi[4];
#pragma unroll
  for (int kk = 0; kk < 4; ++kk) {
    const float* p = x + ((size_t)grow * Tdim + 1) * INdim + kk * 32 + xk0;
    xlo[kk] = *(const f32x4*)p;
    xhi[kk] = *(const f32x4*)(p + 4);
  }

  // --- scan: iter t stages v(t+1) [tag st_tag], stores v(t+2) [tag wt_tag] ---
  unsigned st_tag = 1u, wt_tag = 2u;
  const unsigned* cur = buf0;
  unsigned* nxt = buf1;
  for (int t = 0; t < Tdim; ++t) {
    stage_tagged(cur + (size_t)r * 16 * Hdim, sA, tid, c, st_tag);
    __syncthreads();  // tile complete (remote chunks + everyone's self chunks)
    f32x4 a0 = {0.f, 0.f, 0.f, 0.f}, a1 = a0, a2 = a0, a3 = a0;
#pragma unroll
    for (int kk = 0; kk < 32; kk += 4) {
      a0 = __builtin_amdgcn_mfma_f32_16x16x32_bf16(wrec[kk + 0], afrag(sA, lane, kk + 0), a0, 0, 0, 0);
      a1 = __builtin_amdgcn_mfma_f32_16x16x32_bf16(wrec[kk + 1], afrag(sA, lane, kk + 1), a1, 0, 0, 0);
      a2 = __builtin_amdgcn_mfma_f32_16x16x32_bf16(wrec[kk + 2], afrag(sA, lane, kk + 2), a2, 0, 0, 0);
      a3 = __builtin_amdgcn_mfma_f32_16x16x32_bf16(wrec[kk + 3], afrag(sA, lane, kk + 3), a3, 0, 0, 0);
    }
    f32x4 acc = (a0 + a1) + (a2 + a3);
    f32x4 e = {0.f, 0.f, 0.f, 0.f};
    if (t + 1 < Tdim) {
#pragma unroll
      for (int kk = 0; kk < 4; ++kk)
        e = __builtin_amdgcn_mfma_f32_16x16x32_bf16(win[kk], cvt8(xlo[kk], xhi[kk]), e, 0, 0, 0);
    }
    float v0, v1, v2, v3;
    {
      float s0 = acc[0] + brec4[0], s1 = acc[1] + brec4[1];
      float s2 = acc[2] + brec4[2], s3 = acc[3] + brec4[3];
      s0 = s0 > 0.f ? s0 : 0.f; s1 = s1 > 0.f ? s1 : 0.f;
      s2 = s2 > 0.f ? s2 : 0.f; s3 = s3 > 0.f ? s3 : 0.f;
      if (t + 1 < Tdim) {
        v0 = s0 + e[0] + bin4[0]; v1 = s1 + e[1] + bin4[1];
        v2 = s2 + e[2] + bin4[2]; v3 = s3 + e[3] + bin4[3];
      } else {
        v0 = s0; v1 = s1; v2 = s2; v3 = s3;
      }
    }
    i32x4 w = {(int)tagw(v0, wt_tag), (int)tagw(v1, wt_tag),
               (int)tagw(v2, wt_tag), (int)tagw(v3, wt_tag)};
    st_b128_c(nxt + (size_t)grow * Hdim + colb, w);  // no ack wait needed
    // prefetch x_{t+2} (cached loads; drained by next stage's vmcnt)
    if (t + 2 < Tdim) {
#pragma unroll
      for (int kk = 0; kk < 4; ++kk) {
        const float* p = x + ((size_t)grow * Tdim + (t + 2)) * INdim + kk * 32 + xk0;
        xlo[kk] = *(const f32x4*)p;
        xhi[kk] = *(const f32x4*)(p + 4);
      }
    }
    __syncthreads();  // all afrag reads done before sA is rewritten
    // self-write v(t+2)'s own slice into LDS for the NEXT stage
    *(i32x2*)selfdst = (i32x2){(int)cvt2(w[0], w[1]), (int)cvt2(w[2], w[3])};
    const unsigned* tmp = cur; cur = nxt; nxt = (unsigned*)tmp;
    st_tag = wt_tag;
    wt_tag = (wt_tag == 3u) ? 1u : wt_tag + 1u;
  }

  // --- epilogue: stage v257 (tag st_tag), grid barrier, W_out, broadcast ---
  stage_tagged(cur + (size_t)r * 16 * Hdim, sA, tid, c, st_tag);
  __syncthreads();
  // one-shot grid barrier (tail-scratch safety: nobody overwrites scratch
  // until everyone staged its state into LDS). Proven sc0sc1 flag protocol.
  if (tid == 0) st_b32_c(gflags + (size_t)wg * 16, 1u);
  if (tid < 128) {
    unsigned* f = gflags + (size_t)tid * 16;
    while (ld_b32_c(f) < 1u) __builtin_amdgcn_s_sleep(1);
  }
  __syncthreads();

  f32x4 a0 = {0.f, 0.f, 0.f, 0.f}, a1 = a0;
#pragma unroll
  for (int kk = 0; kk < 32; kk += 2) {
    const float* p0 = W_out + (size_t)colw * Hdim + (kk + 0) * 32 + kgrp * 8;
    const float* p1 = W_out + (size_t)colw * Hdim + (kk + 1) * 32 + kgrp * 8;
    a0 = __builtin_amdgcn_mfma_f32_16x16x32_bf16(
        cvt8(*(const f32x4*)p0, *(const f32x4*)(p0 + 4)), afrag(sA, lane, kk + 0), a0, 0, 0, 0);
    a1 = __builtin_amdgcn_mfma_f32_16x16x32_bf16(
        cvt8(*(const f32x4*)p1, *(const f32x4*)(p1 + 4)), afrag(sA, lane, kk + 1), a1, 0, 0, 0);
  }
  f32x4 acc = a0 + a1;
  f32x4 bo4 = *(const f32x4*)(b_out + colb);
  __syncthreads();  // afrag reads done before sA reuse
  float* sP = (float*)sA;  // 16 x 128 plop tile (f32, 8KB), [batch row][H col]
  *(f32x4*)(sP + (size_t)(lane & 15) * 128 + ww * 16 + kgrp * 4) = acc + bo4;
  __syncthreads();

  int h32 = tid & 31, tloc = tid >> 5;
  for (int b = 0; b < 16; ++b) {
    f32x4 v = *(const f32x4*)(sP + b * 128 + h32 * 4);
#pragma unroll
    for (int tb = 0; tb < 16; ++tb) {
      int t = tb * 16 + tloc;
      *(f32x4*)(out + ((size_t)(16 * r + b) * Tdim + t) * Hdim + 128 * c + h32 * 4) = v;
    }
  }
}

extern "C" void kernel_launch(void* const* d_in, const int* in_sizes, int n_in,
                              void* d_out, int out_size, void* d_ws, size_t ws_size,
                              hipStream_t stream) {
  const float* x = (const float*)d_in[0];
  const float* W_in = (const float*)d_in[1];
  const float* b_in = (const float*)d_in[2];
  const float* W_rec = (const float*)d_in[3];
  const float* b_rec = (const float*)d_in[4];
  const float* W_out = (const float*)d_in[5];
  const float* b_out = (const float*)d_in[6];
  float* out = (float*)d_out;
  (void)in_sizes; (void)n_in; (void)out_size;

  char* scratch = (ws_size >= SCRATCH_BYTES)
                      ? (char*)d_ws
                      : ((char*)d_out + OUT_BYTES - SCRATCH_BYTES);

  // zero counters + BOTH state buffers (tag 0 = never-valid; also clears the
  // 0xAA poison whose tag would alias tag 2). Dispatch-boundary flush makes
  // these visible to the CP readers (proven by rounds 2-7).
  zero_ws<<<dim3(SCRATCH_BYTES / 4096), dim3(256), 0, stream>>>((i32x4*)scratch);
  rnn_fused<<<dim3(128), dim3(512), 0, stream>>>(x, W_in, b_in, W_rec, b_rec,
                                                 W_out, b_out, out, scratch);
}

// Round 9
// 1651.634 us; speedup vs baseline: 1.4357x; 1.4357x over previous
//
#include <hip/hip_runtime.h>

// RNNSequenceEncoder: B=256, T=256, IN=128, H=1024
// Round-9: round-4 protocol (proven best, 1257us) with serialization shaved:
//  - 3-deep state buffer + poll-at-iter-start (overwrite-safety: my store of
//    v(t+2) overwrites v(t-1); start-poll >= t+1 proves peers staged v(t) and
//    earlier, so v(t-1) readers are long gone)
//  - per-WAVE flags: each wave publishes after ITS OWN vmcnt ack (no WG-wide
//    barrier behind the slowest wave before the flag)
//  - per-THREAD poll: a thread's 4 stage chunks come from exactly one
//    producer wave; poll that one flag, then load - fast producers' slices
//    stage while slow ones are still computing. 2 barriers/step (was 3).
//  - stage skips own 4KB slice (self-write regs->LDS); x-prefetch issued
//    before the poll so it hides under the flag wait.
// Lessons kept: sc0sc1 for ALL cross-WG data (rounds 5/6: sc0-only deadlocks);
// no tagged-data retry protocols (round 8: retry floods congest the CP).

#define Bdim 256
#define Tdim 256
#define INdim 128
#define Hdim 1024

typedef __attribute__((ext_vector_type(8))) __bf16 bf16x8;
typedef __attribute__((ext_vector_type(4))) float f32x4;
typedef __attribute__((ext_vector_type(4))) int i32x4;

#define OUT_BYTES ((size_t)Bdim * Tdim * Hdim * 4)   /* 256 MB */
#define SBYTES ((size_t)Bdim * Hdim * 2)             /* one bf16 state buffer: 512 KB */
#define CNT_BYTES 131072
#define SCRATCH_BYTES (CNT_BYTES + 3 * SBYTES)       /* ~1.63 MB */

// --- device-coherent ops (bypass L1+L2; visible device-wide; PROVEN) ---
static __device__ __forceinline__ void st_b16_c(void* p, unsigned v) {
  asm volatile("global_store_short %0, %1, off sc0 sc1" :: "v"(p), "v"(v) : "memory");
}
static __device__ __forceinline__ void st_b32_c(void* p, unsigned v) {
  asm volatile("global_store_dword %0, %1, off sc0 sc1" :: "v"(p), "v"(v) : "memory");
}
static __device__ __forceinline__ unsigned ld_b32_c(const void* p) {
  unsigned v;
  asm volatile("global_load_dword %0, %1, off sc0 sc1\n\ts_waitcnt vmcnt(0)"
               : "=v"(v) : "v"(p) : "memory");
  return v;
}
static __device__ __forceinline__ i32x4 ld_b128_c(const void* p) {
  i32x4 v;
  asm volatile("global_load_dwordx4 %0, %1, off sc0 sc1" : "=v"(v) : "v"(p) : "memory");
  return v;
}
static __device__ __forceinline__ void wait_vm0() {
  asm volatile("s_waitcnt vmcnt(0)" ::: "memory");
}

static __device__ __forceinline__ bf16x8 cvt8(f32x4 lo, f32x4 hi) {
  bf16x8 r;
  r[0] = (__bf16)lo[0]; r[1] = (__bf16)lo[1]; r[2] = (__bf16)lo[2]; r[3] = (__bf16)lo[3];
  r[4] = (__bf16)hi[0]; r[5] = (__bf16)hi[1]; r[6] = (__bf16)hi[2]; r[7] = (__bf16)hi[3];
  return r;
}
static __device__ __forceinline__ unsigned short bfbits(float f) {
  __bf16 b = (__bf16)f;
  return __builtin_bit_cast(unsigned short, b);
}

// state fragment from LDS: lane holds rows[lane&15][k0..k0+7], k0=kk*32+(lane>>4)*8,
// through the XOR swizzle (16B chunk ch at ch ^ (row&7)). A/B use identical
// K-packing so any HW K-permutation cancels. (Proven rounds 2-8.)
static __device__ __forceinline__ bf16x8 afrag(const __bf16* sA, int lane, int kk) {
  int row = lane & 15;
  int chq = kk * 4 + (lane >> 4);
  return *(const bf16x8*)(sA + (size_t)row * Hdim + ((chq ^ (row & 7)) << 3));
}

__global__ void zero_cnt(i32x4* p) {
  p[(size_t)blockIdx.x * 256 + threadIdx.x] = (i32x4){0, 0, 0, 0};
}

__global__ void __launch_bounds__(512, 1)
rnn_fused(const float* __restrict__ x, const float* __restrict__ W_in,
          const float* __restrict__ b_in, const float* __restrict__ W_rec,
          const float* __restrict__ b_rec, const float* __restrict__ W_out,
          const float* __restrict__ b_out, float* __restrict__ out,
          char* __restrict__ scratch) {
  __shared__ __align__(16) __bf16 sA[16 * Hdim];  // 32 KB

  unsigned* counters = (unsigned*)scratch;
  __bf16* buf0 = (__bf16*)(scratch + CNT_BYTES);
  __bf16* buf1 = buf0 + (size_t)Bdim * Hdim;
  __bf16* buf2 = buf1 + (size_t)Bdim * Hdim;

  int wg = blockIdx.x;               // 0..127
  int idx = wg >> 3;
  int r = (wg & 7) + 8 * (idx & 1);  // row block 0..15
  int c = idx >> 1;                  // col chunk 0..7 (128 H cols)
  int tid = threadIdx.x;
  int lane = tid & 63;
  int ww = tid >> 6;                 // wave 0..7
  int kgrp = lane >> 4;

  int col = c * 128 + ww * 16 + (lane & 15);  // H column owned by this lane
  int xrow = 16 * r + (lane & 15);            // batch row for x A-fragments

  // flags: row-block r has 64 per-wave flags (producer wave g = c*8+ww),
  // 64B apart: counters[r*1024 + g*16]. gflags (epilogue) at word 16384.
  unsigned* rbf = counters + (size_t)r * 1024;
  unsigned* myflag = rbf + (size_t)(c * 8 + ww) * 16;
  unsigned* gflags = counters + 16384;

  // stage mapping: thread handles 16B chunks (rows row0,+4,+8,+12; cols
  // [ch*8, ch*8+8)). Producing wave g = ch>>1; own-slice chunks are skipped
  // (self-written from registers).
  int ch = tid & 127;
  int row0 = tid >> 7;
  bool remote = (ch >> 4) != c;
  unsigned* chflag = rbf + (size_t)(ch >> 1) * 16;
  int sw_lo = (ch ^ row0) << 3;        // swizzle for rows row0, row0+8
  int sw_hi = (ch ^ (row0 + 4)) << 3;  // swizzle for rows row0+4, row0+12

  // self-write LDS addresses: lane's 4 values live at (row=kgrp*4+j, col)
  unsigned short* sAu = (unsigned short*)sA;
  int colch = col >> 3, coloff = col & 7;
#define SELF_ADDR(j) ((size_t)(kgrp * 4 + (j)) * Hdim + \
                      (((colch ^ ((kgrp * 4 + (j)) & 7)) << 3) + coloff))

  // --- preload weights (normal cached loads) ---
  bf16x8 wrec[32];  // W_rec row `col`, K=1024 -> 128 VGPRs
#pragma unroll
  for (int kk = 0; kk < 32; ++kk) {
    const float* p = W_rec + (size_t)col * Hdim + kk * 32 + kgrp * 8;
    wrec[kk] = cvt8(*(const f32x4*)p, *(const f32x4*)(p + 4));
  }
  bf16x8 win[4];    // W_in row `col`, K=128
#pragma unroll
  for (int kk = 0; kk < 4; ++kk) {
    const float* p = W_in + (size_t)col * INdim + kk * 32 + kgrp * 8;
    win[kk] = cvt8(*(const f32x4*)p, *(const f32x4*)(p + 4));
  }
  float b_rec_l = b_rec[col];
  float b_in_l = b_in[col];
  int xk0 = kgrp * 8;

  // --- phase 0: v1 = ext_0 -> buf1 (v(k) lives in buf[k%3]) ---
  unsigned short sv0, sv1, sv2, sv3;  // own 4 values of the staged version
  {
    f32x4 e = {0.f, 0.f, 0.f, 0.f};
#pragma unroll
    for (int kk = 0; kk < 4; ++kk) {
      const float* p = x + ((size_t)xrow * Tdim + 0) * INdim + kk * 32 + xk0;
      e = __builtin_amdgcn_mfma_f32_16x16x32_bf16(
          cvt8(*(const f32x4*)p, *(const f32x4*)(p + 4)), win[kk], e, 0, 0, 0);
    }
    sv0 = bfbits(e[0] + b_in_l); sv1 = bfbits(e[1] + b_in_l);
    sv2 = bfbits(e[2] + b_in_l); sv3 = bfbits(e[3] + b_in_l);
    st_b16_c(buf1 + (size_t)(16 * r + kgrp * 4 + 0) * Hdim + col, sv0);
    st_b16_c(buf1 + (size_t)(16 * r + kgrp * 4 + 1) * Hdim + col, sv1);
    st_b16_c(buf1 + (size_t)(16 * r + kgrp * 4 + 2) * Hdim + col, sv2);
    st_b16_c(buf1 + (size_t)(16 * r + kgrp * 4 + 3) * Hdim + col, sv3);
  }
  wait_vm0();                                  // this wave's stores ack'd
  if (lane == 0) st_b32_c(myflag, 1u);         // per-wave publish of v1

  // --- scan: iter t stages v(t+1) from pa, stores v(t+2) to pb ---
  __bf16 *pa = buf1, *pb = buf2, *pc = buf0;
  for (int t = 0; t < Tdim; ++t) {
    // x-prefetch first: hides under the flag wait
    f32x4 xlo[4], xhi[4];
    if (t + 1 < Tdim) {
#pragma unroll
      for (int kk = 0; kk < 4; ++kk) {
        const float* p = x + ((size_t)xrow * Tdim + (t + 1)) * INdim + kk * 32 + xk0;
        xlo[kk] = *(const f32x4*)p;
        xhi[kk] = *(const f32x4*)(p + 4);
      }
    }
    // per-thread: poll ONE producer-wave flag, then load its 4 chunks
    i32x4 d0, d1, d2, d3;
    if (remote) {
      unsigned need = (unsigned)(t + 1);
      while (ld_b32_c(chflag) < need) __builtin_amdgcn_s_sleep(2);
      const __bf16* src = pa + (size_t)r * 16 * Hdim + ch * 8;
      d0 = ld_b128_c(src + (size_t)(row0 + 0) * Hdim);
      d1 = ld_b128_c(src + (size_t)(row0 + 4) * Hdim);
      d2 = ld_b128_c(src + (size_t)(row0 + 8) * Hdim);
      d3 = ld_b128_c(src + (size_t)(row0 + 12) * Hdim);
    }
    wait_vm0();
    __syncthreads();  // #2: all waves done reading sA (prev iter's MFMA)
    if (remote) {
      *(i32x4*)(sA + (size_t)(row0 + 0) * Hdim + sw_lo) = d0;
      *(i32x4*)(sA + (size_t)(row0 + 4) * Hdim + sw_hi) = d1;
      *(i32x4*)(sA + (size_t)(row0 + 8) * Hdim + sw_lo) = d2;
      *(i32x4*)(sA + (size_t)(row0 + 12) * Hdim + sw_hi) = d3;
    }
    sAu[SELF_ADDR(0)] = sv0; sAu[SELF_ADDR(1)] = sv1;
    sAu[SELF_ADDR(2)] = sv2; sAu[SELF_ADDR(3)] = sv3;
    __syncthreads();  // #1: tile complete
    f32x4 a0 = {0.f, 0.f, 0.f, 0.f}, a1 = a0, a2 = a0, a3 = a0;
#pragma unroll
    for (int kk = 0; kk < 32; kk += 4) {
      a0 = __builtin_amdgcn_mfma_f32_16x16x32_bf16(afrag(sA, lane, kk + 0), wrec[kk + 0], a0, 0, 0, 0);
      a1 = __builtin_amdgcn_mfma_f32_16x16x32_bf16(afrag(sA, lane, kk + 1), wrec[kk + 1], a1, 0, 0, 0);
      a2 = __builtin_amdgcn_mfma_f32_16x16x32_bf16(afrag(sA, lane, kk + 2), wrec[kk + 2], a2, 0, 0, 0);
      a3 = __builtin_amdgcn_mfma_f32_16x16x32_bf16(afrag(sA, lane, kk + 3), wrec[kk + 3], a3, 0, 0, 0);
    }
    f32x4 acc = (a0 + a1) + (a2 + a3);
    f32x4 e = {0.f, 0.f, 0.f, 0.f};
    if (t + 1 < Tdim) {
#pragma unroll
      for (int kk = 0; kk < 4; ++kk)
        e = __builtin_amdgcn_mfma_f32_16x16x32_bf16(cvt8(xlo[kk], xhi[kk]), win[kk], e, 0, 0, 0);
    }
    // v(t+2) = relu(acc + b_rec) [+ ext_{t+1}]; C/D: col=lane&15, row=kgrp*4+j
    {
      float s0 = acc[0] + b_rec_l, s1 = acc[1] + b_rec_l;
      float s2 = acc[2] + b_rec_l, s3 = acc[3] + b_rec_l;
      s0 = s0 > 0.f ? s0 : 0.f; s1 = s1 > 0.f ? s1 : 0.f;
      s2 = s2 > 0.f ? s2 : 0.f; s3 = s3 > 0.f ? s3 : 0.f;
      if (t + 1 < Tdim) {
        s0 += e[0] + b_in_l; s1 += e[1] + b_in_l;
        s2 += e[2] + b_in_l; s3 += e[3] + b_in_l;
      }
      sv0 = bfbits(s0); sv1 = bfbits(s1); sv2 = bfbits(s2); sv3 = bfbits(s3);
    }
    st_b16_c(pb + (size_t)(16 * r + kgrp * 4 + 0) * Hdim + col, sv0);
    st_b16_c(pb + (size_t)(16 * r + kgrp * 4 + 1) * Hdim + col, sv1);
    st_b16_c(pb + (size_t)(16 * r + kgrp * 4 + 2) * Hdim + col, sv2);
    st_b16_c(pb + (size_t)(16 * r + kgrp * 4 + 3) * Hdim + col, sv3);
    wait_vm0();                                        // this wave ack'd
    if (lane == 0) st_b32_c(myflag, (unsigned)(t + 2)); // per-wave publish
    __bf16* tmp = pa; pa = pb; pb = pc; pc = tmp;       // 3-buffer rotate
  }

  // --- epilogue: stage v257 (in pa), grid barrier, W_out, broadcast ---
  {
    i32x4 d0, d1, d2, d3;
    if (remote) {
      while (ld_b32_c(chflag) < 257u) __builtin_amdgcn_s_sleep(2);
      const __bf16* src = pa + (size_t)r * 16 * Hdim + ch * 8;
      d0 = ld_b128_c(src + (size_t)(row0 + 0) * Hdim);
      d1 = ld_b128_c(src + (size_t)(row0 + 4) * Hdim);
      d2 = ld_b128_c(src + (size_t)(row0 + 8) * Hdim);
      d3 = ld_b128_c(src + (size_t)(row0 + 12) * Hdim);
    }
    wait_vm0();
    __syncthreads();
    if (remote) {
      *(i32x4*)(sA + (size_t)(row0 + 0) * Hdim + sw_lo) = d0;
      *(i32x4*)(sA + (size_t)(row0 + 4) * Hdim + sw_hi) = d1;
      *(i32x4*)(sA + (size_t)(row0 + 8) * Hdim + sw_lo) = d2;
      *(i32x4*)(sA + (size_t)(row0 + 12) * Hdim + sw_hi) = d3;
    }
    sAu[SELF_ADDR(0)] = sv0; sAu[SELF_ADDR(1)] = sv1;
    sAu[SELF_ADDR(2)] = sv2; sAu[SELF_ADDR(3)] = sv3;
    __syncthreads();
  }
  // one-shot grid barrier (tail-scratch safety: nobody overwrites scratch
  // with output until everyone staged its state into LDS). Proven protocol.
  if (tid == 0) st_b32_c(gflags + (size_t)wg * 16, 1u);
  if (tid < 128) {
    unsigned* f = gflags + (size_t)tid * 16;
    while (ld_b32_c(f) < 1u) __builtin_amdgcn_s_sleep(1);
  }
  __syncthreads();

  f32x4 a0 = {0.f, 0.f, 0.f, 0.f}, a1 = a0;
#pragma unroll
  for (int kk = 0; kk < 32; kk += 2) {
    const float* p0 = W_out + (size_t)col * Hdim + (kk + 0) * 32 + kgrp * 8;
    const float* p1 = W_out + (size_t)col * Hdim + (kk + 1) * 32 + kgrp * 8;
    a0 = __builtin_amdgcn_mfma_f32_16x16x32_bf16(
        afrag(sA, lane, kk + 0), cvt8(*(const f32x4*)p0, *(const f32x4*)(p0 + 4)), a0, 0, 0, 0);
    a1 = __builtin_amdgcn_mfma_f32_16x16x32_bf16(
        afrag(sA, lane, kk + 1), cvt8(*(const f32x4*)p1, *(const f32x4*)(p1 + 4)), a1, 0, 0, 0);
  }
  f32x4 acc = a0 + a1;
  float bo = b_out[col];
  __syncthreads();  // afrag reads done before sA reuse
  float* sP = (float*)sA;  // 16 x 128 plop tile (f32, 8KB), [batch row][col]
#pragma unroll
  for (int j = 0; j < 4; ++j)
    sP[(kgrp * 4 + j) * 128 + ww * 16 + (lane & 15)] = acc[j] + bo;
  __syncthreads();

  int h32 = tid & 31, tloc = tid >> 5;
  for (int b = 0; b < 16; ++b) {
    f32x4 v = *(const f32x4*)(sP + b * 128 + h32 * 4);
#pragma unroll
    for (int tb = 0; tb < 16; ++tb) {
      int t = tb * 16 + tloc;
      *(f32x4*)(out + ((size_t)(16 * r + b) * Tdim + t) * Hdim + 128 * c + h32 * 4) = v;
    }
  }
}

extern "C" void kernel_launch(void* const* d_in, const int* in_sizes, int n_in,
                              void* d_out, int out_size, void* d_ws, size_t ws_size,
                              hipStream_t stream) {
  const float* x = (const float*)d_in[0];
  const float* W_in = (const float*)d_in[1];
  const float* b_in = (const float*)d_in[2];
  const float* W_rec = (const float*)d_in[3];
  const float* b_rec = (const float*)d_in[4];
  const float* W_out = (const float*)d_in[5];
  const float* b_out = (const float*)d_in[6];
  float* out = (float*)d_out;
  (void)in_sizes; (void)n_in; (void)out_size;

  char* scratch = (ws_size >= SCRATCH_BYTES)
                      ? (char*)d_ws
                      : ((char*)d_out + OUT_BYTES - SCRATCH_BYTES);

  // zero the flag region (128 KB); state buffers need no init (flag-gated)
  zero_cnt<<<dim3(CNT_BYTES / 4096), dim3(256), 0, stream>>>((i32x4*)scratch);
  rnn_fused<<<dim3(128), dim3(512), 0, stream>>>(x, W_in, b_in, W_rec, b_rec,
                                                 W_out, b_out, out, scratch);
}